// Round 4
// baseline (1018.399 us; speedup 1.0000x reference)
//
#include <hip/hip_runtime.h>

// ---------------------------------------------------------------------------
// In2MA: windowed dual attention. B=4, C=64, H=W=256, WIN=8, HEADS=8, INNER=64
// One 256-thread block per window. R4: all-fp16 LDS activations + single-f16
// weights (fp16 rounding is 8x finer than bf16; R1's all-bf16 absmax 0.0547
// scales to ~0.007, 5x under threshold). mfma_f32_16x16x32_f16, 1 MFMA/k-tile.
// LDS 43008 B -> 3 blocks/CU. fp32 kept only in accumulators / softmax / gate
// arithmetic (all in registers).
// ---------------------------------------------------------------------------

typedef _Float16 h8_t __attribute__((ext_vector_type(8)));  // MFMA A/B frag
typedef _Float16 h4_t __attribute__((ext_vector_type(4)));
typedef __attribute__((ext_vector_type(4))) float floatx4;  // MFMA accum

#define CCH  64
#define HH   256
#define WWD  256
#define HWsz (HH*WWD)
#define CHW  (CCH*HH*WWD)

// weight element offsets (single f16 plane)
#define OWPQ  0      // W_pan_q    32x32
#define OWPK  1024   // W_pan_k    32x32
#define OWV1  2048   // W_v1       64x64
#define OWV2  6144   // W_v2       64x64
#define OWK2  10240  // W_k2       32x64
#define OWQ1C 12288  // W_q1c      32x64
#define OWK1C 14336  // W_k1c      32x64
#define OWIO  16384  // W_inner_out 64x64
#define OWINT 20480  // W_inter_out 64x64
#define WTOT  24576

// ---------------------------------------------------------------------------
// proj: O(64xN) = A(64xK) @ W(NxK)^T. A,O: f16 LDS (elem strides SA/SO, rows
// 16B-aligned). W: f16 global row-major NxK. fp32 accum. Wave w owns output
// rows [16w,16w+16): A-reads and O-writes strip-local -> chained proj calls
// need no barrier. MFMA 16x16x32 layouts (m89/m120, dtype-independent):
//   A: lane holds A[m=lane&15][k=quad*8+j]; B: lane holds W[n=lane&15][k]
//   D: lane holds D[row=quad*4+r][col=lane&15]
// ---------------------------------------------------------------------------
template <int K, int N, int SA, int SO>
__device__ __forceinline__ void proj(const _Float16* __restrict__ A,
                                     const _Float16* __restrict__ W,
                                     _Float16* __restrict__ O,
                                     int wave, int lane) {
    constexpr int KS = K / 32;
    constexpr int NT = N / 16;
    const int l15 = lane & 15;
    const int quad = lane >> 4;
    const int m0 = wave * 16;

    h8_t af[KS];
#pragma unroll
    for (int kk = 0; kk < KS; ++kk)
        af[kk] = *(const h8_t*)(A + (m0 + l15) * SA + kk * 32 + quad * 8);

#pragma unroll
    for (int nt = 0; nt < NT; ++nt) {
        floatx4 acc = {0.f, 0.f, 0.f, 0.f};
#pragma unroll
        for (int kk = 0; kk < KS; ++kk) {
            h8_t bf = *(const h8_t*)(W + (nt * 16 + l15) * K + kk * 32 + quad * 8);
            acc = __builtin_amdgcn_mfma_f32_16x16x32_f16(af[kk], bf, acc, 0, 0, 0);
        }
#pragma unroll
        for (int r = 0; r < 4; ++r)
            O[(m0 + quad * 4 + r) * SO + nt * 16 + l15] = (_Float16)acc[r];
    }
}

// ---------------------------------------------------------------------------
// Weight fp32 -> f16 (once per launch; ws re-poisoned each call)
// ---------------------------------------------------------------------------
__global__ void cvt_w(const float* __restrict__ w0, const float* __restrict__ w1,
                      const float* __restrict__ w2, const float* __restrict__ w3,
                      const float* __restrict__ w4, const float* __restrict__ w5,
                      const float* __restrict__ w6, const float* __restrict__ w7,
                      const float* __restrict__ w8, _Float16* __restrict__ o) {
    int i = blockIdx.x * 256 + threadIdx.x;
    const float* src; int off;
    if      (i < 1024)  { src = w0; off = 0; }
    else if (i < 2048)  { src = w1; off = 1024; }
    else if (i < 6144)  { src = w2; off = 2048; }
    else if (i < 10240) { src = w3; off = 6144; }
    else if (i < 12288) { src = w4; off = 10240; }
    else if (i < 14336) { src = w5; off = 12288; }
    else if (i < 16384) { src = w6; off = 14336; }
    else if (i < 20480) { src = w7; off = 16384; }
    else                { src = w8; off = 20480; }
    o[i] = (_Float16)src[i - off];
}

// ---------------------------------------------------------------------------
// LDS plan (all f16, 43008 B -> 3 blocks/CU). Strides keep rows 16B-aligned.
//  s_xf [64*72] 9216 B: xf -> out1
//  s_cat[64*72] 9216 B: pan(c0-31)+q1c(c32-63) -> cat -> out2
//  s_v1 [64*72] 9216 B: v1 -> x_v2 -> final
//  s_pq [64*40] 5120 B: pan_q                         [phA..S8]
//  s_pk [64*40] 5120 B: pan_k                         [phA..S3]
//  s_k2 [64*40] 5120 B: k1c -> x_k2                   [phA..S8]
// ---------------------------------------------------------------------------
__global__ __launch_bounds__(256, 3) void in2ma_main(
    const float* __restrict__ x, const float* __restrict__ pan,
    const float* __restrict__ posi, const float* __restrict__ posc,
    const _Float16* __restrict__ wb, float* __restrict__ out) {
    __shared__ __align__(16) _Float16 s_xf[64 * 72];
    __shared__ __align__(16) _Float16 s_cat[64 * 72];
    __shared__ __align__(16) _Float16 s_v1[64 * 72];
    __shared__ __align__(16) _Float16 s_pq[64 * 40];
    __shared__ __align__(16) _Float16 s_pk[64 * 40];
    __shared__ __align__(16) _Float16 s_k2[64 * 40];

    const int tid  = threadIdx.x;
    const int wave = tid >> 6;
    const int lane = tid & 63;
    const int wid  = blockIdx.x;
    const int b    = wid >> 10;
    const int hn_i = (wid >> 5) & 31;
    const int wn_i = wid & 31;
    const int h0 = hn_i * 8, w0 = wn_i * 8;

    const float scale = 0.35355339059327373f;  // 8^-0.5 (both attentions)

    // ---- S0: stage x -> s_xf, pan -> s_cat cols 0-31 (f16) ----
    {
        const int c = tid >> 2, i = tid & 3;
        const float* xp = x + (size_t)b * CHW + (size_t)c * HWsz + (size_t)h0 * WWD + w0;
#pragma unroll
        for (int r = 0; r < 2; ++r) {
            const int hl = i * 2 + r;
            const float4* p = (const float4*)(xp + hl * WWD);
            float4 a = p[0], q = p[1];
            _Float16* d = s_xf + (hl * 8) * 72 + c;
            d[0 * 72] = (_Float16)a.x; d[1 * 72] = (_Float16)a.y;
            d[2 * 72] = (_Float16)a.z; d[3 * 72] = (_Float16)a.w;
            d[4 * 72] = (_Float16)q.x; d[5 * 72] = (_Float16)q.y;
            d[6 * 72] = (_Float16)q.z; d[7 * 72] = (_Float16)q.w;
        }
        if (tid < 128) {
            const int c2 = tid >> 2, i2 = tid & 3;
            const float* pp = pan + (size_t)b * (CHW / 2) + (size_t)c2 * HWsz + (size_t)h0 * WWD + w0;
#pragma unroll
            for (int r = 0; r < 2; ++r) {
                const int hl = i2 * 2 + r;
                const float4* p = (const float4*)(pp + hl * WWD);
                float4 a = p[0], q = p[1];
                _Float16* d = s_cat + (hl * 8) * 72 + c2;
                d[0 * 72] = (_Float16)a.x; d[1 * 72] = (_Float16)a.y;
                d[2 * 72] = (_Float16)a.z; d[3 * 72] = (_Float16)a.w;
                d[4 * 72] = (_Float16)q.x; d[5 * 72] = (_Float16)q.y;
                d[6 * 72] = (_Float16)q.z; d[7 * 72] = (_Float16)q.w;
            }
        }
    }
    __syncthreads();

    // ---- Phase A: projections (strip-local; no intra-phase barriers).
    // NB pan_q/pan_k read cat cols 0-31 (K=32) BEFORE q1c writes cols 32-63.
    proj<32, 32, 72, 40>(s_cat, wb + OWPQ,  s_pq,       wave, lane); // pan_q
    proj<32, 32, 72, 40>(s_cat, wb + OWPK,  s_pk,       wave, lane); // pan_k
    proj<64, 64, 72, 72>(s_xf,  wb + OWV1,  s_v1,       wave, lane); // x_v1
    proj<64, 32, 72, 72>(s_xf,  wb + OWQ1C, s_cat + 32, wave, lane); // q1c
    proj<64, 32, 72, 40>(s_xf,  wb + OWK1C, s_k2,       wave, lane); // k1c
    __syncthreads();

    // ---- S3: pan MHA (8 heads, d=4, seq=64), fused single-pass softmax*V.
    // wave w: heads w, w+4. Lane = query token. K/V reads are wave-broadcast.
#pragma unroll
    for (int hh = 0; hh < 2; ++hh) {
        const int h = wave + hh * 4;
        h4_t q4 = *(const h4_t*)(s_pq + lane * 40 + 4 * h);
        const float q0 = (float)q4.x, q1 = (float)q4.y,
                    q2 = (float)q4.z, q3 = (float)q4.w;
        const float4* pp4 = (const float4*)(posi + h * 4096 + lane * 64);
        float s = 0.f, o0 = 0.f, o1 = 0.f, o2 = 0.f, o3 = 0.f;
#pragma unroll
        for (int t4 = 0; t4 < 16; ++t4) {
            float4 pv = pp4[t4];
            float pvv[4] = {pv.x, pv.y, pv.z, pv.w};
#pragma unroll
            for (int u = 0; u < 4; ++u) {
                const int t = t4 * 4 + u;
                h4_t kv = *(const h4_t*)(s_pk + t * 40 + 4 * h);
                h4_t vv = *(const h4_t*)(s_v1 + t * 72 + 4 * h);
                float d = q0 * (float)kv.x + q1 * (float)kv.y +
                          q2 * (float)kv.z + q3 * (float)kv.w;
                float e = __expf(d * scale + pvv[u]);
                s += e;
                o0 += e * (float)vv.x; o1 += e * (float)vv.y;
                o2 += e * (float)vv.z; o3 += e * (float)vv.w;
            }
        }
        const float inv = 1.f / s;
        h4_t ov; ov.x = (_Float16)(o0 * inv); ov.y = (_Float16)(o1 * inv);
        ov.z = (_Float16)(o2 * inv); ov.w = (_Float16)(o3 * inv);
        *(h4_t*)(s_cat + lane * 72 + 4 * h) = ov;  // cat cols [0,32)
    }

    // ---- S5: color MHA (seq=32 channels, d=8 token-dims), head rows are the
    // wave's own strip -> no barrier needed between S3 and S5.
    {
        const int h = wave * 2 + (lane >> 5);
        const int i = lane & 31;
        float q[8];
#pragma unroll
        for (int j = 0; j < 8; ++j) q[j] = (float)s_cat[(8 * h + j) * 72 + 32 + i];  // q1c
        float lr[32];
#pragma unroll
        for (int j = 0; j < 8; ++j) {
            const _Float16* kp = s_k2 + (8 * h + j) * 40;  // k1c row, broadcast
            const float qj = q[j];
#pragma unroll
            for (int t4 = 0; t4 < 8; ++t4) {
                h4_t kv = *(const h4_t*)(kp + 4 * t4);
                if (j == 0) {
                    lr[4 * t4] = qj * (float)kv.x; lr[4 * t4 + 1] = qj * (float)kv.y;
                    lr[4 * t4 + 2] = qj * (float)kv.z; lr[4 * t4 + 3] = qj * (float)kv.w;
                } else {
                    lr[4 * t4] += qj * (float)kv.x; lr[4 * t4 + 1] += qj * (float)kv.y;
                    lr[4 * t4 + 2] += qj * (float)kv.z; lr[4 * t4 + 3] += qj * (float)kv.w;
                }
            }
        }
        const float4* pp4 = (const float4*)(posc + h * 1024 + i * 32);
        float s = 0.f;
#pragma unroll
        for (int t4 = 0; t4 < 8; ++t4) {
            float4 pv = pp4[t4];
            float pvv[4] = {pv.x, pv.y, pv.z, pv.w};
#pragma unroll
            for (int u = 0; u < 4; ++u) {
                const int t = t4 * 4 + u;
                float e = __expf(lr[t] * scale + pvv[u]);
                lr[t] = e; s += e;
            }
        }
        const float inv = 1.f / s;
#pragma unroll
        for (int j = 0; j < 8; ++j) {
            const _Float16* vp = s_v1 + (8 * h + j) * 72 + 32;  // v1_color, broadcast
            float acc = 0.f;
#pragma unroll
            for (int t4 = 0; t4 < 8; ++t4) {
                h4_t vv = *(const h4_t*)(vp + 4 * t4);
                acc += lr[4 * t4] * (float)vv.x + lr[4 * t4 + 1] * (float)vv.y +
                       lr[4 * t4 + 2] * (float)vv.z + lr[4 * t4 + 3] * (float)vv.w;
            }
            s_cat[(8 * h + j) * 72 + 32 + i] = (_Float16)(acc * inv);
        }
    }
    __syncthreads();

    // ---- Phase C: out1 = cat@Wio^T ; x_v2 = out1@Wv2^T ; x_k2 = out1@Wk2^T ----
    proj<64, 64, 72, 72>(s_cat, wb + OWIO, s_xf, wave, lane);  // out1
    proj<64, 64, 72, 72>(s_xf,  wb + OWV2, s_v1, wave, lane);  // x_v2
    proj<64, 32, 72, 40>(s_xf,  wb + OWK2, s_k2, wave, lane);  // x_k2
    __syncthreads();

    // ---- S8: inter attention (cosine gate). thread -> (token t, heads hb, hb+4) ----
    {
        const int t = tid & 63;
        const int hb = tid >> 6;
#pragma unroll
        for (int r = 0; r < 2; ++r) {
            const int h = hb + r * 4;
            h4_t qv = *(const h4_t*)(s_pq + t * 40 + 4 * h);   // pan_q
            h4_t kv = *(const h4_t*)(s_k2 + t * 40 + 4 * h);   // x_k2
            float q0 = (float)qv.x, q1 = (float)qv.y, q2 = (float)qv.z, q3 = (float)qv.w;
            float k0 = (float)kv.x, k1 = (float)kv.y, k2 = (float)kv.z, k3 = (float)kv.w;
            float qq = q0 * q0 + q1 * q1 + q2 * q2 + q3 * q3;
            float kk = k0 * k0 + k1 * k1 + k2 * k2 + k3 * k3;
            float qk = q0 * k0 + q1 * k1 + q2 * k2 + q3 * k3;
            float cosv = qk * rsqrtf(qq * kk);
            h8_t vv = *(const h8_t*)(s_v1 + t * 72 + 8 * h);   // x_v2
            h8_t ov;
#pragma unroll
            for (int j = 0; j < 8; ++j) ov[j] = (_Float16)(cosv * (float)vv[j]);
            *(h8_t*)(s_cat + t * 72 + 8 * h) = ov;             // out2
        }
    }
    __syncthreads();

    // ---- S9: final = out2 @ Wint^T -> s_v1 (x_v2 dead) ----
    proj<64, 64, 72, 72>(s_cat, wb + OWINT, s_v1, wave, lane);
    __syncthreads();

    // ---- store: LDS transpose -> coalesced fp32 float4 stores ----
    {
        const int c = tid >> 2, i = tid & 3;
        float* op = out + (size_t)b * CHW + (size_t)c * HWsz + (size_t)h0 * WWD + w0;
#pragma unroll
        for (int r = 0; r < 2; ++r) {
            const int hl = i * 2 + r;
            float v[8];
#pragma unroll
            for (int wl = 0; wl < 8; ++wl)
                v[wl] = (float)s_v1[(hl * 8 + wl) * 72 + c];
            float4* q = (float4*)(op + hl * WWD);
            float4 q0; q0.x = v[0]; q0.y = v[1]; q0.z = v[2]; q0.w = v[3];
            float4 q1; q1.x = v[4]; q1.y = v[5]; q1.z = v[6]; q1.w = v[7];
            q[0] = q0; q[1] = q1;
        }
    }
}

extern "C" void kernel_launch(void* const* d_in, const int* in_sizes, int n_in,
                              void* d_out, int out_size, void* d_ws, size_t ws_size,
                              hipStream_t stream) {
    (void)in_sizes; (void)n_in; (void)out_size; (void)ws_size;
    const float* x    = (const float*)d_in[0];
    const float* pan  = (const float*)d_in[1];
    const float* posi = (const float*)d_in[11];
    const float* posc = (const float*)d_in[12];
    _Float16* wb = (_Float16*)d_ws;  // WTOT*2 = 49152 B of ws

    cvt_w<<<WTOT / 256, 256, 0, stream>>>(
        (const float*)d_in[2], (const float*)d_in[3], (const float*)d_in[4],
        (const float*)d_in[5], (const float*)d_in[6], (const float*)d_in[7],
        (const float*)d_in[8], (const float*)d_in[9], (const float*)d_in[10], wb);

    in2ma_main<<<4096, 256, 0, stream>>>(x, pan, posi, posc, wb, (float*)d_out);
}

// Round 5
// 711.314 us; speedup vs baseline: 1.4317x; 1.4317x over previous
//
#include <hip/hip_runtime.h>

// ---------------------------------------------------------------------------
// In2MA: windowed dual attention. B=4, C=64, H=W=256, WIN=8, HEADS=8, INNER=64
// One 256-thread block per window. R5 = R4 with __launch_bounds__(256,2):
// R4's (256,3) made the allocator target ~84 VGPRs and spill lr[32] to
// scratch (+1.2 GB HBM writes, dur 912us). (256,2) gave 128 VGPR spill-free
// in R2; LDS (43008 B) still allows 3 blocks/CU regardless of the bound.
// All-fp16 LDS activations + f16 weights, mfma_f32_16x16x32_f16 (abs 0.0078).
// ---------------------------------------------------------------------------

typedef _Float16 h8_t __attribute__((ext_vector_type(8)));  // MFMA A/B frag
typedef _Float16 h4_t __attribute__((ext_vector_type(4)));
typedef __attribute__((ext_vector_type(4))) float floatx4;  // MFMA accum

#define CCH  64
#define HH   256
#define WWD  256
#define HWsz (HH*WWD)
#define CHW  (CCH*HH*WWD)

// weight element offsets (single f16 plane)
#define OWPQ  0      // W_pan_q    32x32
#define OWPK  1024   // W_pan_k    32x32
#define OWV1  2048   // W_v1       64x64
#define OWV2  6144   // W_v2       64x64
#define OWK2  10240  // W_k2       32x64
#define OWQ1C 12288  // W_q1c      32x64
#define OWK1C 14336  // W_k1c      32x64
#define OWIO  16384  // W_inner_out 64x64
#define OWINT 20480  // W_inter_out 64x64
#define WTOT  24576

// ---------------------------------------------------------------------------
// proj: O(64xN) = A(64xK) @ W(NxK)^T. A,O: f16 LDS (elem strides SA/SO, rows
// 16B-aligned). W: f16 global row-major NxK. fp32 accum. Wave w owns output
// rows [16w,16w+16): A-reads and O-writes strip-local -> chained proj calls
// need no barrier. MFMA 16x16x32 layouts (m89/m120, dtype-independent):
//   A: lane holds A[m=lane&15][k=quad*8+j]; B: lane holds W[n=lane&15][k]
//   D: lane holds D[row=quad*4+r][col=lane&15]
// ---------------------------------------------------------------------------
template <int K, int N, int SA, int SO>
__device__ __forceinline__ void proj(const _Float16* __restrict__ A,
                                     const _Float16* __restrict__ W,
                                     _Float16* __restrict__ O,
                                     int wave, int lane) {
    constexpr int KS = K / 32;
    constexpr int NT = N / 16;
    const int l15 = lane & 15;
    const int quad = lane >> 4;
    const int m0 = wave * 16;

    h8_t af[KS];
#pragma unroll
    for (int kk = 0; kk < KS; ++kk)
        af[kk] = *(const h8_t*)(A + (m0 + l15) * SA + kk * 32 + quad * 8);

#pragma unroll
    for (int nt = 0; nt < NT; ++nt) {
        floatx4 acc = {0.f, 0.f, 0.f, 0.f};
#pragma unroll
        for (int kk = 0; kk < KS; ++kk) {
            h8_t bf = *(const h8_t*)(W + (nt * 16 + l15) * K + kk * 32 + quad * 8);
            acc = __builtin_amdgcn_mfma_f32_16x16x32_f16(af[kk], bf, acc, 0, 0, 0);
        }
#pragma unroll
        for (int r = 0; r < 4; ++r)
            O[(m0 + quad * 4 + r) * SO + nt * 16 + l15] = (_Float16)acc[r];
    }
}

// ---------------------------------------------------------------------------
// Weight fp32 -> f16 (once per launch; ws re-poisoned each call)
// ---------------------------------------------------------------------------
__global__ void cvt_w(const float* __restrict__ w0, const float* __restrict__ w1,
                      const float* __restrict__ w2, const float* __restrict__ w3,
                      const float* __restrict__ w4, const float* __restrict__ w5,
                      const float* __restrict__ w6, const float* __restrict__ w7,
                      const float* __restrict__ w8, _Float16* __restrict__ o) {
    int i = blockIdx.x * 256 + threadIdx.x;
    const float* src; int off;
    if      (i < 1024)  { src = w0; off = 0; }
    else if (i < 2048)  { src = w1; off = 1024; }
    else if (i < 6144)  { src = w2; off = 2048; }
    else if (i < 10240) { src = w3; off = 6144; }
    else if (i < 12288) { src = w4; off = 10240; }
    else if (i < 14336) { src = w5; off = 12288; }
    else if (i < 16384) { src = w6; off = 14336; }
    else if (i < 20480) { src = w7; off = 16384; }
    else                { src = w8; off = 20480; }
    o[i] = (_Float16)src[i - off];
}

// ---------------------------------------------------------------------------
// LDS plan (all f16, 43008 B -> 3 blocks/CU). Strides keep rows 16B-aligned.
//  s_xf [64*72] 9216 B: xf -> out1
//  s_cat[64*72] 9216 B: pan(c0-31)+q1c(c32-63) -> cat -> out2
//  s_v1 [64*72] 9216 B: v1 -> x_v2 -> final
//  s_pq [64*40] 5120 B: pan_q                         [phA..S8]
//  s_pk [64*40] 5120 B: pan_k                         [phA..S3]
//  s_k2 [64*40] 5120 B: k1c -> x_k2                   [phA..S8]
// ---------------------------------------------------------------------------
__global__ __launch_bounds__(256, 2) void in2ma_main(
    const float* __restrict__ x, const float* __restrict__ pan,
    const float* __restrict__ posi, const float* __restrict__ posc,
    const _Float16* __restrict__ wb, float* __restrict__ out) {
    __shared__ __align__(16) _Float16 s_xf[64 * 72];
    __shared__ __align__(16) _Float16 s_cat[64 * 72];
    __shared__ __align__(16) _Float16 s_v1[64 * 72];
    __shared__ __align__(16) _Float16 s_pq[64 * 40];
    __shared__ __align__(16) _Float16 s_pk[64 * 40];
    __shared__ __align__(16) _Float16 s_k2[64 * 40];

    const int tid  = threadIdx.x;
    const int wave = tid >> 6;
    const int lane = tid & 63;
    const int wid  = blockIdx.x;
    const int b    = wid >> 10;
    const int hn_i = (wid >> 5) & 31;
    const int wn_i = wid & 31;
    const int h0 = hn_i * 8, w0 = wn_i * 8;

    const float scale = 0.35355339059327373f;  // 8^-0.5 (both attentions)

    // ---- S0: stage x -> s_xf, pan -> s_cat cols 0-31 (f16) ----
    {
        const int c = tid >> 2, i = tid & 3;
        const float* xp = x + (size_t)b * CHW + (size_t)c * HWsz + (size_t)h0 * WWD + w0;
#pragma unroll
        for (int r = 0; r < 2; ++r) {
            const int hl = i * 2 + r;
            const float4* p = (const float4*)(xp + hl * WWD);
            float4 a = p[0], q = p[1];
            _Float16* d = s_xf + (hl * 8) * 72 + c;
            d[0 * 72] = (_Float16)a.x; d[1 * 72] = (_Float16)a.y;
            d[2 * 72] = (_Float16)a.z; d[3 * 72] = (_Float16)a.w;
            d[4 * 72] = (_Float16)q.x; d[5 * 72] = (_Float16)q.y;
            d[6 * 72] = (_Float16)q.z; d[7 * 72] = (_Float16)q.w;
        }
        if (tid < 128) {
            const int c2 = tid >> 2, i2 = tid & 3;
            const float* pp = pan + (size_t)b * (CHW / 2) + (size_t)c2 * HWsz + (size_t)h0 * WWD + w0;
#pragma unroll
            for (int r = 0; r < 2; ++r) {
                const int hl = i2 * 2 + r;
                const float4* p = (const float4*)(pp + hl * WWD);
                float4 a = p[0], q = p[1];
                _Float16* d = s_cat + (hl * 8) * 72 + c2;
                d[0 * 72] = (_Float16)a.x; d[1 * 72] = (_Float16)a.y;
                d[2 * 72] = (_Float16)a.z; d[3 * 72] = (_Float16)a.w;
                d[4 * 72] = (_Float16)q.x; d[5 * 72] = (_Float16)q.y;
                d[6 * 72] = (_Float16)q.z; d[7 * 72] = (_Float16)q.w;
            }
        }
    }
    __syncthreads();

    // ---- Phase A: projections (strip-local; no intra-phase barriers).
    // NB pan_q/pan_k read cat cols 0-31 (K=32) BEFORE q1c writes cols 32-63.
    proj<32, 32, 72, 40>(s_cat, wb + OWPQ,  s_pq,       wave, lane); // pan_q
    proj<32, 32, 72, 40>(s_cat, wb + OWPK,  s_pk,       wave, lane); // pan_k
    proj<64, 64, 72, 72>(s_xf,  wb + OWV1,  s_v1,       wave, lane); // x_v1
    proj<64, 32, 72, 72>(s_xf,  wb + OWQ1C, s_cat + 32, wave, lane); // q1c
    proj<64, 32, 72, 40>(s_xf,  wb + OWK1C, s_k2,       wave, lane); // k1c
    __syncthreads();

    // ---- S3: pan MHA (8 heads, d=4, seq=64), fused single-pass softmax*V.
    // wave w: heads w, w+4. Lane = query token. K/V reads are wave-broadcast.
#pragma unroll
    for (int hh = 0; hh < 2; ++hh) {
        const int h = wave + hh * 4;
        h4_t q4 = *(const h4_t*)(s_pq + lane * 40 + 4 * h);
        const float q0 = (float)q4.x, q1 = (float)q4.y,
                    q2 = (float)q4.z, q3 = (float)q4.w;
        const float4* pp4 = (const float4*)(posi + h * 4096 + lane * 64);
        float s = 0.f, o0 = 0.f, o1 = 0.f, o2 = 0.f, o3 = 0.f;
#pragma unroll
        for (int t4 = 0; t4 < 16; ++t4) {
            float4 pv = pp4[t4];
            float pvv[4] = {pv.x, pv.y, pv.z, pv.w};
#pragma unroll
            for (int u = 0; u < 4; ++u) {
                const int t = t4 * 4 + u;
                h4_t kv = *(const h4_t*)(s_pk + t * 40 + 4 * h);
                h4_t vv = *(const h4_t*)(s_v1 + t * 72 + 4 * h);
                float d = q0 * (float)kv.x + q1 * (float)kv.y +
                          q2 * (float)kv.z + q3 * (float)kv.w;
                float e = __expf(d * scale + pvv[u]);
                s += e;
                o0 += e * (float)vv.x; o1 += e * (float)vv.y;
                o2 += e * (float)vv.z; o3 += e * (float)vv.w;
            }
        }
        const float inv = 1.f / s;
        h4_t ov; ov.x = (_Float16)(o0 * inv); ov.y = (_Float16)(o1 * inv);
        ov.z = (_Float16)(o2 * inv); ov.w = (_Float16)(o3 * inv);
        *(h4_t*)(s_cat + lane * 72 + 4 * h) = ov;  // cat cols [0,32)
    }

    // ---- S5: color MHA (seq=32 channels, d=8 token-dims), head rows are the
    // wave's own strip -> no barrier needed between S3 and S5.
    {
        const int h = wave * 2 + (lane >> 5);
        const int i = lane & 31;
        float q[8];
#pragma unroll
        for (int j = 0; j < 8; ++j) q[j] = (float)s_cat[(8 * h + j) * 72 + 32 + i];  // q1c
        float lr[32];
#pragma unroll
        for (int j = 0; j < 8; ++j) {
            const _Float16* kp = s_k2 + (8 * h + j) * 40;  // k1c row, broadcast
            const float qj = q[j];
#pragma unroll
            for (int t4 = 0; t4 < 8; ++t4) {
                h4_t kv = *(const h4_t*)(kp + 4 * t4);
                if (j == 0) {
                    lr[4 * t4] = qj * (float)kv.x; lr[4 * t4 + 1] = qj * (float)kv.y;
                    lr[4 * t4 + 2] = qj * (float)kv.z; lr[4 * t4 + 3] = qj * (float)kv.w;
                } else {
                    lr[4 * t4] += qj * (float)kv.x; lr[4 * t4 + 1] += qj * (float)kv.y;
                    lr[4 * t4 + 2] += qj * (float)kv.z; lr[4 * t4 + 3] += qj * (float)kv.w;
                }
            }
        }
        const float4* pp4 = (const float4*)(posc + h * 1024 + i * 32);
        float s = 0.f;
#pragma unroll
        for (int t4 = 0; t4 < 8; ++t4) {
            float4 pv = pp4[t4];
            float pvv[4] = {pv.x, pv.y, pv.z, pv.w};
#pragma unroll
            for (int u = 0; u < 4; ++u) {
                const int t = t4 * 4 + u;
                float e = __expf(lr[t] * scale + pvv[u]);
                lr[t] = e; s += e;
            }
        }
        const float inv = 1.f / s;
#pragma unroll
        for (int j = 0; j < 8; ++j) {
            const _Float16* vp = s_v1 + (8 * h + j) * 72 + 32;  // v1_color, broadcast
            float acc = 0.f;
#pragma unroll
            for (int t4 = 0; t4 < 8; ++t4) {
                h4_t vv = *(const h4_t*)(vp + 4 * t4);
                acc += lr[4 * t4] * (float)vv.x + lr[4 * t4 + 1] * (float)vv.y +
                       lr[4 * t4 + 2] * (float)vv.z + lr[4 * t4 + 3] * (float)vv.w;
            }
            s_cat[(8 * h + j) * 72 + 32 + i] = (_Float16)(acc * inv);
        }
    }
    __syncthreads();

    // ---- Phase C: out1 = cat@Wio^T ; x_v2 = out1@Wv2^T ; x_k2 = out1@Wk2^T ----
    proj<64, 64, 72, 72>(s_cat, wb + OWIO, s_xf, wave, lane);  // out1
    proj<64, 64, 72, 72>(s_xf,  wb + OWV2, s_v1, wave, lane);  // x_v2
    proj<64, 32, 72, 40>(s_xf,  wb + OWK2, s_k2, wave, lane);  // x_k2
    __syncthreads();

    // ---- S8: inter attention (cosine gate). thread -> (token t, heads hb, hb+4) ----
    {
        const int t = tid & 63;
        const int hb = tid >> 6;
#pragma unroll
        for (int r = 0; r < 2; ++r) {
            const int h = hb + r * 4;
            h4_t qv = *(const h4_t*)(s_pq + t * 40 + 4 * h);   // pan_q
            h4_t kv = *(const h4_t*)(s_k2 + t * 40 + 4 * h);   // x_k2
            float q0 = (float)qv.x, q1 = (float)qv.y, q2 = (float)qv.z, q3 = (float)qv.w;
            float k0 = (float)kv.x, k1 = (float)kv.y, k2 = (float)kv.z, k3 = (float)kv.w;
            float qq = q0 * q0 + q1 * q1 + q2 * q2 + q3 * q3;
            float kk = k0 * k0 + k1 * k1 + k2 * k2 + k3 * k3;
            float qk = q0 * k0 + q1 * k1 + q2 * k2 + q3 * k3;
            float cosv = qk * rsqrtf(qq * kk);
            h8_t vv = *(const h8_t*)(s_v1 + t * 72 + 8 * h);   // x_v2
            h8_t ov;
#pragma unroll
            for (int j = 0; j < 8; ++j) ov[j] = (_Float16)(cosv * (float)vv[j]);
            *(h8_t*)(s_cat + t * 72 + 8 * h) = ov;             // out2
        }
    }
    __syncthreads();

    // ---- S9: final = out2 @ Wint^T -> s_v1 (x_v2 dead) ----
    proj<64, 64, 72, 72>(s_cat, wb + OWINT, s_v1, wave, lane);
    __syncthreads();

    // ---- store: LDS transpose -> coalesced fp32 float4 stores ----
    {
        const int c = tid >> 2, i = tid & 3;
        float* op = out + (size_t)b * CHW + (size_t)c * HWsz + (size_t)h0 * WWD + w0;
#pragma unroll
        for (int r = 0; r < 2; ++r) {
            const int hl = i * 2 + r;
            float v[8];
#pragma unroll
            for (int wl = 0; wl < 8; ++wl)
                v[wl] = (float)s_v1[(hl * 8 + wl) * 72 + c];
            float4* q = (float4*)(op + hl * WWD);
            float4 q0; q0.x = v[0]; q0.y = v[1]; q0.z = v[2]; q0.w = v[3];
            float4 q1; q1.x = v[4]; q1.y = v[5]; q1.z = v[6]; q1.w = v[7];
            q[0] = q0; q[1] = q1;
        }
    }
}

extern "C" void kernel_launch(void* const* d_in, const int* in_sizes, int n_in,
                              void* d_out, int out_size, void* d_ws, size_t ws_size,
                              hipStream_t stream) {
    (void)in_sizes; (void)n_in; (void)out_size; (void)ws_size;
    const float* x    = (const float*)d_in[0];
    const float* pan  = (const float*)d_in[1];
    const float* posi = (const float*)d_in[11];
    const float* posc = (const float*)d_in[12];
    _Float16* wb = (_Float16*)d_ws;  // WTOT*2 = 49152 B of ws

    cvt_w<<<WTOT / 256, 256, 0, stream>>>(
        (const float*)d_in[2], (const float*)d_in[3], (const float*)d_in[4],
        (const float*)d_in[5], (const float*)d_in[6], (const float*)d_in[7],
        (const float*)d_in[8], (const float*)d_in[9], (const float*)d_in[10], wb);

    in2ma_main<<<4096, 256, 0, stream>>>(x, pan, posi, posc, wb, (float*)d_out);
}

// Round 6
// 671.501 us; speedup vs baseline: 1.5166x; 1.0593x over previous
//
#include <hip/hip_runtime.h>

// ---------------------------------------------------------------------------
// In2MA: windowed dual attention. B=4, C=64, H=W=256, WIN=8, HEADS=8, INNER=64
// One 256-thread block per window. R6 = R5 + sched_barrier(0) fences between
// phases/proj calls. Theory: R5's slim projs let the scheduler hoist weight
// B-frag global loads across all six inlined projs -> register blowup ->
// scratch spill (WRITE_SIZE 938 MB vs 90 MB legit, occupancy capped at 2
// blocks/CU). Coarse sched fences stop cross-proj code motion.
// All-fp16 LDS activations + f16 weights, mfma_f32_16x16x32_f16 (abs 0.0078).
// ---------------------------------------------------------------------------

typedef _Float16 h8_t __attribute__((ext_vector_type(8)));  // MFMA A/B frag
typedef _Float16 h4_t __attribute__((ext_vector_type(4)));
typedef __attribute__((ext_vector_type(4))) float floatx4;  // MFMA accum

#define CCH  64
#define HH   256
#define WWD  256
#define HWsz (HH*WWD)
#define CHW  (CCH*HH*WWD)

#define SCHED_FENCE() __builtin_amdgcn_sched_barrier(0)

// weight element offsets (single f16 plane)
#define OWPQ  0      // W_pan_q    32x32
#define OWPK  1024   // W_pan_k    32x32
#define OWV1  2048   // W_v1       64x64
#define OWV2  6144   // W_v2       64x64
#define OWK2  10240  // W_k2       32x64
#define OWQ1C 12288  // W_q1c      32x64
#define OWK1C 14336  // W_k1c      32x64
#define OWIO  16384  // W_inner_out 64x64
#define OWINT 20480  // W_inter_out 64x64
#define WTOT  24576

// ---------------------------------------------------------------------------
// proj: O(64xN) = A(64xK) @ W(NxK)^T. A,O: f16 LDS (elem strides SA/SO, rows
// 16B-aligned). W: f16 global row-major NxK. fp32 accum. Wave w owns output
// rows [16w,16w+16): A-reads and O-writes strip-local -> chained proj calls
// need no barrier. MFMA 16x16x32 layouts (m89/m120, dtype-independent):
//   A: lane holds A[m=lane&15][k=quad*8+j]; B: lane holds W[n=lane&15][k]
//   D: lane holds D[row=quad*4+r][col=lane&15]
// ---------------------------------------------------------------------------
template <int K, int N, int SA, int SO>
__device__ __forceinline__ void proj(const _Float16* __restrict__ A,
                                     const _Float16* __restrict__ W,
                                     _Float16* __restrict__ O,
                                     int wave, int lane) {
    constexpr int KS = K / 32;
    constexpr int NT = N / 16;
    const int l15 = lane & 15;
    const int quad = lane >> 4;
    const int m0 = wave * 16;

    h8_t af[KS];
#pragma unroll
    for (int kk = 0; kk < KS; ++kk)
        af[kk] = *(const h8_t*)(A + (m0 + l15) * SA + kk * 32 + quad * 8);

#pragma unroll
    for (int nt = 0; nt < NT; ++nt) {
        floatx4 acc = {0.f, 0.f, 0.f, 0.f};
#pragma unroll
        for (int kk = 0; kk < KS; ++kk) {
            h8_t bf = *(const h8_t*)(W + (nt * 16 + l15) * K + kk * 32 + quad * 8);
            acc = __builtin_amdgcn_mfma_f32_16x16x32_f16(af[kk], bf, acc, 0, 0, 0);
        }
#pragma unroll
        for (int r = 0; r < 4; ++r)
            O[(m0 + quad * 4 + r) * SO + nt * 16 + l15] = (_Float16)acc[r];
    }
}

// ---------------------------------------------------------------------------
// Weight fp32 -> f16 (once per launch; ws re-poisoned each call)
// ---------------------------------------------------------------------------
__global__ void cvt_w(const float* __restrict__ w0, const float* __restrict__ w1,
                      const float* __restrict__ w2, const float* __restrict__ w3,
                      const float* __restrict__ w4, const float* __restrict__ w5,
                      const float* __restrict__ w6, const float* __restrict__ w7,
                      const float* __restrict__ w8, _Float16* __restrict__ o) {
    int i = blockIdx.x * 256 + threadIdx.x;
    const float* src; int off;
    if      (i < 1024)  { src = w0; off = 0; }
    else if (i < 2048)  { src = w1; off = 1024; }
    else if (i < 6144)  { src = w2; off = 2048; }
    else if (i < 10240) { src = w3; off = 6144; }
    else if (i < 12288) { src = w4; off = 10240; }
    else if (i < 14336) { src = w5; off = 12288; }
    else if (i < 16384) { src = w6; off = 14336; }
    else if (i < 20480) { src = w7; off = 16384; }
    else                { src = w8; off = 20480; }
    o[i] = (_Float16)src[i - off];
}

// ---------------------------------------------------------------------------
// LDS plan (all f16, 43008 B). Strides keep rows 16B-aligned.
//  s_xf [64*72] 9216 B: xf -> out1
//  s_cat[64*72] 9216 B: pan(c0-31)+q1c(c32-63) -> cat -> out2
//  s_v1 [64*72] 9216 B: v1 -> x_v2 -> final
//  s_pq [64*40] 5120 B: pan_q                         [phA..S8]
//  s_pk [64*40] 5120 B: pan_k                         [phA..S3]
//  s_k2 [64*40] 5120 B: k1c -> x_k2                   [phA..S8]
// ---------------------------------------------------------------------------
__global__ __launch_bounds__(256, 2) void in2ma_main(
    const float* __restrict__ x, const float* __restrict__ pan,
    const float* __restrict__ posi, const float* __restrict__ posc,
    const _Float16* __restrict__ wb, float* __restrict__ out) {
    __shared__ __align__(16) _Float16 s_xf[64 * 72];
    __shared__ __align__(16) _Float16 s_cat[64 * 72];
    __shared__ __align__(16) _Float16 s_v1[64 * 72];
    __shared__ __align__(16) _Float16 s_pq[64 * 40];
    __shared__ __align__(16) _Float16 s_pk[64 * 40];
    __shared__ __align__(16) _Float16 s_k2[64 * 40];

    const int tid  = threadIdx.x;
    const int wave = tid >> 6;
    const int lane = tid & 63;
    const int wid  = blockIdx.x;
    const int b    = wid >> 10;
    const int hn_i = (wid >> 5) & 31;
    const int wn_i = wid & 31;
    const int h0 = hn_i * 8, w0 = wn_i * 8;

    const float scale = 0.35355339059327373f;  // 8^-0.5 (both attentions)

    // ---- S0: stage x -> s_xf, pan -> s_cat cols 0-31 (f16) ----
    {
        const int c = tid >> 2, i = tid & 3;
        const float* xp = x + (size_t)b * CHW + (size_t)c * HWsz + (size_t)h0 * WWD + w0;
#pragma unroll
        for (int r = 0; r < 2; ++r) {
            const int hl = i * 2 + r;
            const float4* p = (const float4*)(xp + hl * WWD);
            float4 a = p[0], q = p[1];
            _Float16* d = s_xf + (hl * 8) * 72 + c;
            d[0 * 72] = (_Float16)a.x; d[1 * 72] = (_Float16)a.y;
            d[2 * 72] = (_Float16)a.z; d[3 * 72] = (_Float16)a.w;
            d[4 * 72] = (_Float16)q.x; d[5 * 72] = (_Float16)q.y;
            d[6 * 72] = (_Float16)q.z; d[7 * 72] = (_Float16)q.w;
        }
        if (tid < 128) {
            const int c2 = tid >> 2, i2 = tid & 3;
            const float* pp = pan + (size_t)b * (CHW / 2) + (size_t)c2 * HWsz + (size_t)h0 * WWD + w0;
#pragma unroll
            for (int r = 0; r < 2; ++r) {
                const int hl = i2 * 2 + r;
                const float4* p = (const float4*)(pp + hl * WWD);
                float4 a = p[0], q = p[1];
                _Float16* d = s_cat + (hl * 8) * 72 + c2;
                d[0 * 72] = (_Float16)a.x; d[1 * 72] = (_Float16)a.y;
                d[2 * 72] = (_Float16)a.z; d[3 * 72] = (_Float16)a.w;
                d[4 * 72] = (_Float16)q.x; d[5 * 72] = (_Float16)q.y;
                d[6 * 72] = (_Float16)q.z; d[7 * 72] = (_Float16)q.w;
            }
        }
    }
    __syncthreads();

    // ---- Phase A: projections (strip-local; no intra-phase barriers).
    // sched_barrier(0) between calls: keep each proj's weight loads local so
    // the scheduler can't hoist all six projs' B-frags into one live window.
    proj<32, 32, 72, 40>(s_cat, wb + OWPQ,  s_pq,       wave, lane); // pan_q
    SCHED_FENCE();
    proj<32, 32, 72, 40>(s_cat, wb + OWPK,  s_pk,       wave, lane); // pan_k
    SCHED_FENCE();
    proj<64, 64, 72, 72>(s_xf,  wb + OWV1,  s_v1,       wave, lane); // x_v1
    SCHED_FENCE();
    proj<64, 32, 72, 72>(s_xf,  wb + OWQ1C, s_cat + 32, wave, lane); // q1c
    SCHED_FENCE();
    proj<64, 32, 72, 40>(s_xf,  wb + OWK1C, s_k2,       wave, lane); // k1c
    SCHED_FENCE();
    __syncthreads();

    // ---- S3: pan MHA (8 heads, d=4, seq=64), fused single-pass softmax*V.
    // wave w: heads w, w+4. Lane = query token. K/V reads are wave-broadcast.
#pragma unroll
    for (int hh = 0; hh < 2; ++hh) {
        const int h = wave + hh * 4;
        h4_t q4 = *(const h4_t*)(s_pq + lane * 40 + 4 * h);
        const float q0 = (float)q4.x, q1 = (float)q4.y,
                    q2 = (float)q4.z, q3 = (float)q4.w;
        const float4* pp4 = (const float4*)(posi + h * 4096 + lane * 64);
        float s = 0.f, o0 = 0.f, o1 = 0.f, o2 = 0.f, o3 = 0.f;
#pragma unroll
        for (int t4 = 0; t4 < 16; ++t4) {
            float4 pv = pp4[t4];
            float pvv[4] = {pv.x, pv.y, pv.z, pv.w};
#pragma unroll
            for (int u = 0; u < 4; ++u) {
                const int t = t4 * 4 + u;
                h4_t kv = *(const h4_t*)(s_pk + t * 40 + 4 * h);
                h4_t vv = *(const h4_t*)(s_v1 + t * 72 + 4 * h);
                float d = q0 * (float)kv.x + q1 * (float)kv.y +
                          q2 * (float)kv.z + q3 * (float)kv.w;
                float e = __expf(d * scale + pvv[u]);
                s += e;
                o0 += e * (float)vv.x; o1 += e * (float)vv.y;
                o2 += e * (float)vv.z; o3 += e * (float)vv.w;
            }
        }
        const float inv = 1.f / s;
        h4_t ov; ov.x = (_Float16)(o0 * inv); ov.y = (_Float16)(o1 * inv);
        ov.z = (_Float16)(o2 * inv); ov.w = (_Float16)(o3 * inv);
        *(h4_t*)(s_cat + lane * 72 + 4 * h) = ov;  // cat cols [0,32)
        SCHED_FENCE();
    }

    // ---- S5: color MHA (seq=32 channels, d=8 token-dims), head rows are the
    // wave's own strip -> no barrier needed between S3 and S5.
    {
        const int h = wave * 2 + (lane >> 5);
        const int i = lane & 31;
        float q[8];
#pragma unroll
        for (int j = 0; j < 8; ++j) q[j] = (float)s_cat[(8 * h + j) * 72 + 32 + i];  // q1c
        float lr[32];
#pragma unroll
        for (int j = 0; j < 8; ++j) {
            const _Float16* kp = s_k2 + (8 * h + j) * 40;  // k1c row, broadcast
            const float qj = q[j];
#pragma unroll
            for (int t4 = 0; t4 < 8; ++t4) {
                h4_t kv = *(const h4_t*)(kp + 4 * t4);
                if (j == 0) {
                    lr[4 * t4] = qj * (float)kv.x; lr[4 * t4 + 1] = qj * (float)kv.y;
                    lr[4 * t4 + 2] = qj * (float)kv.z; lr[4 * t4 + 3] = qj * (float)kv.w;
                } else {
                    lr[4 * t4] += qj * (float)kv.x; lr[4 * t4 + 1] += qj * (float)kv.y;
                    lr[4 * t4 + 2] += qj * (float)kv.z; lr[4 * t4 + 3] += qj * (float)kv.w;
                }
            }
        }
        SCHED_FENCE();
        const float4* pp4 = (const float4*)(posc + h * 1024 + i * 32);
        float s = 0.f;
#pragma unroll
        for (int t4 = 0; t4 < 8; ++t4) {
            float4 pv = pp4[t4];
            float pvv[4] = {pv.x, pv.y, pv.z, pv.w};
#pragma unroll
            for (int u = 0; u < 4; ++u) {
                const int t = t4 * 4 + u;
                float e = __expf(lr[t] * scale + pvv[u]);
                lr[t] = e; s += e;
            }
        }
        const float inv = 1.f / s;
#pragma unroll
        for (int j = 0; j < 8; ++j) {
            const _Float16* vp = s_v1 + (8 * h + j) * 72 + 32;  // v1_color, broadcast
            float acc = 0.f;
#pragma unroll
            for (int t4 = 0; t4 < 8; ++t4) {
                h4_t vv = *(const h4_t*)(vp + 4 * t4);
                acc += lr[4 * t4] * (float)vv.x + lr[4 * t4 + 1] * (float)vv.y +
                       lr[4 * t4 + 2] * (float)vv.z + lr[4 * t4 + 3] * (float)vv.w;
            }
            s_cat[(8 * h + j) * 72 + 32 + i] = (_Float16)(acc * inv);
        }
    }
    __syncthreads();

    // ---- Phase C: out1 = cat@Wio^T ; x_v2 = out1@Wv2^T ; x_k2 = out1@Wk2^T ----
    proj<64, 64, 72, 72>(s_cat, wb + OWIO, s_xf, wave, lane);  // out1
    SCHED_FENCE();
    proj<64, 64, 72, 72>(s_xf,  wb + OWV2, s_v1, wave, lane);  // x_v2
    SCHED_FENCE();
    proj<64, 32, 72, 40>(s_xf,  wb + OWK2, s_k2, wave, lane);  // x_k2
    SCHED_FENCE();
    __syncthreads();

    // ---- S8: inter attention (cosine gate). thread -> (token t, heads hb, hb+4) ----
    {
        const int t = tid & 63;
        const int hb = tid >> 6;
#pragma unroll
        for (int r = 0; r < 2; ++r) {
            const int h = hb + r * 4;
            h4_t qv = *(const h4_t*)(s_pq + t * 40 + 4 * h);   // pan_q
            h4_t kv = *(const h4_t*)(s_k2 + t * 40 + 4 * h);   // x_k2
            float q0 = (float)qv.x, q1 = (float)qv.y, q2 = (float)qv.z, q3 = (float)qv.w;
            float k0 = (float)kv.x, k1 = (float)kv.y, k2 = (float)kv.z, k3 = (float)kv.w;
            float qq = q0 * q0 + q1 * q1 + q2 * q2 + q3 * q3;
            float kk = k0 * k0 + k1 * k1 + k2 * k2 + k3 * k3;
            float qk = q0 * k0 + q1 * k1 + q2 * k2 + q3 * k3;
            float cosv = qk * rsqrtf(qq * kk);
            h8_t vv = *(const h8_t*)(s_v1 + t * 72 + 8 * h);   // x_v2
            h8_t ov;
#pragma unroll
            for (int j = 0; j < 8; ++j) ov[j] = (_Float16)(cosv * (float)vv[j]);
            *(h8_t*)(s_cat + t * 72 + 8 * h) = ov;             // out2
        }
    }
    __syncthreads();

    // ---- S9: final = out2 @ Wint^T -> s_v1 (x_v2 dead) ----
    proj<64, 64, 72, 72>(s_cat, wb + OWINT, s_v1, wave, lane);
    SCHED_FENCE();
    __syncthreads();

    // ---- store: LDS transpose -> coalesced fp32 float4 stores ----
    {
        const int c = tid >> 2, i = tid & 3;
        float* op = out + (size_t)b * CHW + (size_t)c * HWsz + (size_t)h0 * WWD + w0;
#pragma unroll
        for (int r = 0; r < 2; ++r) {
            const int hl = i * 2 + r;
            float v[8];
#pragma unroll
            for (int wl = 0; wl < 8; ++wl)
                v[wl] = (float)s_v1[(hl * 8 + wl) * 72 + c];
            float4* q = (float4*)(op + hl * WWD);
            float4 q0; q0.x = v[0]; q0.y = v[1]; q0.z = v[2]; q0.w = v[3];
            float4 q1; q1.x = v[4]; q1.y = v[5]; q1.z = v[6]; q1.w = v[7];
            q[0] = q0; q[1] = q1;
        }
    }
}

extern "C" void kernel_launch(void* const* d_in, const int* in_sizes, int n_in,
                              void* d_out, int out_size, void* d_ws, size_t ws_size,
                              hipStream_t stream) {
    (void)in_sizes; (void)n_in; (void)out_size; (void)ws_size;
    const float* x    = (const float*)d_in[0];
    const float* pan  = (const float*)d_in[1];
    const float* posi = (const float*)d_in[11];
    const float* posc = (const float*)d_in[12];
    _Float16* wb = (_Float16*)d_ws;  // WTOT*2 = 49152 B of ws

    cvt_w<<<WTOT / 256, 256, 0, stream>>>(
        (const float*)d_in[2], (const float*)d_in[3], (const float*)d_in[4],
        (const float*)d_in[5], (const float*)d_in[6], (const float*)d_in[7],
        (const float*)d_in[8], (const float*)d_in[9], (const float*)d_in[10], wb);

    in2ma_main<<<4096, 256, 0, stream>>>(x, pan, posi, posc, wb, (float*)d_out);
}